// Round 10
// baseline (161.104 us; speedup 1.0000x reference)
//
#include <hip/hip_runtime.h>
#include <hip/hip_bf16.h>

#define BB 16384
#define EE 16
#define HH 256
#define CC 64
#define XD 320   // H + C
#define FH 1024  // 4H
#define CNTP 16  // cnt padding stride (one counter per 64B line)
#define MT 144   // tokens per tile (9 x 16)

typedef __attribute__((ext_vector_type(8))) short short8;
typedef __attribute__((ext_vector_type(4))) float f32x4;

__device__ inline unsigned short bfu(float x) {
    union { __hip_bfloat16 b; unsigned short u; } c;
    c.b = __float2bfloat16(x);
    return c.u;
}

// raw workgroup barrier: drains LDS ops only, leaves global loads in flight
__device__ inline void wg_barrier() {
    asm volatile("s_waitcnt lgkmcnt(0)" ::: "memory");
    __builtin_amdgcn_s_barrier();
    asm volatile("" ::: "memory");
}

// ---------------- anchor normalize ----------------
__global__ void anorm_kernel(const float* __restrict__ anchor, float* __restrict__ anorm) {
    int lane = threadIdx.x & 63;
    int wv = threadIdx.x >> 6;
    for (int e = wv; e < EE; e += 4) {
        float a = anchor[e * CC + lane];
        float s = a * a;
        #pragma unroll
        for (int off = 1; off < 64; off <<= 1) s += __shfl_xor(s, off, 64);
        anorm[e * CC + lane] = a / fmaxf(sqrtf(s), 1e-8f);
    }
}

// ---------------- router: 16 tokens x 16 experts per block, no atomics ----------------
__global__ __launch_bounds__(256) void router_kernel(
    const float* __restrict__ code_emb, const float* __restrict__ gumbel,
    const float* __restrict__ anorm,
    float* __restrict__ topw, int* __restrict__ tope)
{
    __shared__ float an_s[EE][68];
    __shared__ float ce_s[16][68];
    __shared__ float inrm[16];
    const int tid = threadIdx.x;

    {
        int idx = tid * 4;
        int r = idx >> 6, k = idx & 63;
        *(float4*)&an_s[r][k] = *(const float4*)&anorm[idx];
        *(float4*)&ce_s[r][k] = *(const float4*)&code_emb[blockIdx.x * 1024 + idx];
    }
    __syncthreads();

    const int tok = tid >> 4;
    const int e = tid & 15;
    if (e == 0) {
        float s = 0.f;
        #pragma unroll
        for (int k = 0; k < 64; ++k) { float c = ce_s[tok][k]; s += c * c; }
        inrm[tok] = 0.125f / fmaxf(sqrtf(s), 1e-8f);
    }
    __syncthreads();

    float dot = 0.f;
    #pragma unroll
    for (int k = 0; k < 64; ++k) dot += ce_s[tok][k] * an_s[e][k];

    const int b = blockIdx.x * 16 + tok;
    float z = (dot * inrm[tok] + gumbel[b * EE + e]) * 2.0f;  // /TAU, TAU=0.5

    float m = z;
    #pragma unroll
    for (int off = 1; off < 16; off <<= 1) m = fmaxf(m, __shfl_xor(m, off, 64));
    float p = expf(z - m);
    float s = p;
    #pragma unroll
    for (int off = 1; off < 16; off <<= 1) s += __shfl_xor(s, off, 64);
    float w = p / s;

    const int lbase = (tid & 63) & 48;
    float best = -1.f, second = -1.f;
    int bi = 0, si = 0;
    #pragma unroll
    for (int j = 0; j < EE; ++j) {
        float wj = __shfl(w, lbase + j, 64);
        if (wj > best) { second = best; si = bi; best = wj; bi = j; }
        else if (wj > second) { second = wj; si = j; }
    }
    if (e == 0) {
        topw[b * 2] = best;       tope[b * 2] = bi;
        topw[b * 2 + 1] = second; tope[b * 2 + 1] = si;
    }
}

// ---------------- counting-sort assignment: 512 pairs per block ----------------
__global__ __launch_bounds__(256) void assign_kernel(
    const int* __restrict__ tope, int* __restrict__ list, int* __restrict__ cnt)
{
    __shared__ int lcnt[EE];
    __shared__ int base[EE];
    const int tid = threadIdx.x;
    if (tid < EE) lcnt[tid] = 0;
    __syncthreads();
    const int p0 = blockIdx.x * 512;
    const int e0 = tope[p0 + tid];
    const int e1 = tope[p0 + 256 + tid];
    const int r0 = atomicAdd(&lcnt[e0], 1);
    const int r1 = atomicAdd(&lcnt[e1], 1);
    __syncthreads();
    if (tid < EE) base[tid] = atomicAdd(&cnt[tid * CNTP], lcnt[tid]);
    __syncthreads();
    list[e0 * BB + base[e0] + r0] = p0 + tid;
    list[e1 * BB + base[e1] + r1] = p0 + 256 + tid;
}

// ---------------- weight conversion f32 -> bf16 ----------------
__global__ void convert_w_kernel(const float* __restrict__ W1, const float* __restrict__ W2,
                                 __hip_bfloat16* __restrict__ W1bf, __hip_bfloat16* __restrict__ W2bf) {
    int i = blockIdx.x * blockDim.x + threadIdx.x;
    const int n1 = EE * FH * XD / 4;
    const int n2 = EE * HH * FH / 4;
    if (i < n1) {
        float4 v = ((const float4*)W1)[i];
        ushort4 o; o.x = bfu(v.x); o.y = bfu(v.y); o.z = bfu(v.z); o.w = bfu(v.w);
        ((ushort4*)W1bf)[i] = o;
    } else if (i < n1 + n2) {
        int j = i - n1;
        float4 v = ((const float4*)W2)[j];
        ushort4 o; o.x = bfu(v.x); o.y = bfu(v.y); o.z = bfu(v.z); o.w = bfu(v.w);
        ((ushort4*)W2bf)[j] = o;
    }
}

// ---------------- x = concat(h, code_emb) -> bf16 ----------------
__global__ void convert_x_kernel(const float* __restrict__ h, const float* __restrict__ ce,
                                 __hip_bfloat16* __restrict__ xbf) {
    int i = blockIdx.x * blockDim.x + threadIdx.x;
    const int n = BB * XD / 4;
    if (i >= n) return;
    int i4 = i * 4;
    int b = i4 / XD;
    int c = i4 % XD;
    float4 v;
    if (c < HH) v = *(const float4*)&h[b * HH + c];
    else        v = *(const float4*)&ce[b * CC + (c - HH)];
    ushort4 o; o.x = bfu(v.x); o.y = bfu(v.y); o.z = bfu(v.z); o.w = bfu(v.w);
    ((ushort4*)xbf)[i] = o;
}

// ---------------- aux loss: 64-block partial + tiny final (deterministic) ----------------
__global__ __launch_bounds__(256) void aux_partial_kernel(const float* __restrict__ topw,
                                                          const int* __restrict__ tope,
                                                          float* __restrict__ partial) {
    __shared__ float ls[256][EE + 1];
    int tid = threadIdx.x;
    #pragma unroll
    for (int e = 0; e < EE; ++e) ls[tid][e] = 0.f;
    int i0 = blockIdx.x * 512 + tid;
    ls[tid][tope[i0]] += topw[i0];
    ls[tid][tope[i0 + 256]] += topw[i0 + 256];
    __syncthreads();
    if (tid < EE) {
        float s = 0.f;
        for (int r = 0; r < 256; ++r) s += ls[r][tid];
        partial[blockIdx.x * EE + tid] = s;
    }
}

__global__ void aux_final_kernel(const float* __restrict__ partial, float* __restrict__ out) {
    __shared__ float counts[EE];
    int tid = threadIdx.x;
    if (tid < EE) {
        float s = 0.f;
        for (int bk = 0; bk < 64; ++bk) s += partial[bk * EE + tid];
        counts[tid] = s;
    }
    __syncthreads();
    if (tid == 0) {
        float total = 0.f;
        for (int e = 0; e < EE; ++e) total += counts[e];
        float mean = total / EE;
        float var = 0.f;
        for (int e = 0; e < EE; ++e) { float d = counts[e] - mean; var += d * d; }
        var /= (EE - 1);
        float ent = 0.f;
        for (int e = 0; e < EE; ++e) { float ld = counts[e] / total; ent -= ld * logf(ld + 1e-12f); }
        out[(size_t)BB * HH] = 0.5f * (sqrtf(var) + ent);
    }
}

// ---------------- fused sparse MoE MLP: 144-tok tiles, pipelined chunks ----------------
// Grid 256 = 16 experts x 16 blocks; one tile per block (capacity 2304 = +5.8
// sigma). 8 waves split N per 128-col chunk. Chunk pipeline: peel GEMM1(0) and
// GEMM2(7); loop body = [merged GEMM2(oc-1)+GEMM1(oc) region] bar [GELU(oc)]
// bar -- the fat region co-schedules both GEMMs' LDS reads, MFMAs and the
// weight loads (R9 kept them in separate one-pipe phases). hs permutation
// p=(row^(row>>2))&7 makes BOTH the GELU writes and GEMM2 reads bank-uniform
// (R9's row&7 exposed only kg-bit0 on writes -> 4-way conflict, 2.17M cycles).
__global__ __launch_bounds__(512, 2) void moe_kernel(
    const __hip_bfloat16* __restrict__ xbf,
    const __hip_bfloat16* __restrict__ W1bf,
    const __hip_bfloat16* __restrict__ W2bf,
    const float* __restrict__ b1, const float* __restrict__ b2,
    const int* __restrict__ list, const int* __restrict__ cnt,
    const float* __restrict__ topw,
    __hip_bfloat16* __restrict__ tmp)
{
    __shared__ __hip_bfloat16 xs[MT * 320];   // 90 KB, XOR-swizzled 16B granules
    __shared__ __hip_bfloat16 hs[MT * 128];   // 36 KB, single buffer, perm-swizzled
    const int e = blockIdx.x & 15;   // XCD = bid%8 = e%8
    const int t0 = blockIdx.x >> 4;  // 0..15
    const int n = cnt[e * CNTP];
    const int ntiles = (n + MT - 1) / MT;
    const int tid = threadIdx.x;
    const int lane = tid & 63;
    const int wv = tid >> 6;     // 0..7
    const int l15 = lane & 15;
    const int kg = lane >> 4;    // 0..3
    const int lr7 = l15 & 7;

    const __hip_bfloat16* w1r = W1bf + (size_t)e * FH * XD + (size_t)(wv * 16 + l15) * XD + kg * 8;
    const __hip_bfloat16* w2r = W2bf + (size_t)e * HH * FH + (size_t)(wv * 32 + l15) * FH + kg * 8;
    const float* b1r = b1 + e * FH + wv * 16 + l15;
    float b2v[2];
    b2v[0] = b2[e * HH + wv * 32 + l15];
    b2v[1] = b2[e * HH + wv * 32 + 16 + l15];
    float b1s[8];
    #pragma unroll
    for (int oc = 0; oc < 8; ++oc) b1s[oc] = b1r[oc * 128];

    // per-mi hs read permutation (row = mi*16 + l15)
    int hp[9];
    #pragma unroll
    for (int mi = 0; mi < 9; ++mi) {
        int row = mi * 16 + l15;
        hp[mi] = (row ^ (row >> 2)) & 7;
    }
    const int cgw = 2 * wv + (l15 >> 3);  // write col granule base

    f32x4 acc[9][2];
    f32x4 pre[9];
    short8 f2[8];

    // GEMM1 K-step for chunk base w1c
    auto g1step = [&](const short8& f1k, int ks) {
        #pragma unroll
        for (int mi = 0; mi < 9; ++mi) {
            short8 a = *(const short8*)&xs[(mi * 16 + l15) * 320 + (((ks * 4 + kg) ^ lr7) << 3)];
            pre[mi] = __builtin_amdgcn_mfma_f32_16x16x32_bf16(a, f1k, pre[mi], 0, 0, 0);
        }
    };
    // GEMM2 K-step (consumes hs of previous chunk + f2)
    auto g2step = [&](int ks) {
        #pragma unroll
        for (int mi = 0; mi < 9; ++mi) {
            short8 a2 = *(const short8*)&hs[(mi * 16 + l15) * 128 + ((((ks * 4 + kg) ^ hp[mi])) << 3)];
            acc[mi][0] = __builtin_amdgcn_mfma_f32_16x16x32_bf16(a2, f2[ks], acc[mi][0], 0, 0, 0);
            acc[mi][1] = __builtin_amdgcn_mfma_f32_16x16x32_bf16(a2, f2[4 + ks], acc[mi][1], 0, 0, 0);
        }
    };
    auto loadf2 = [&](int oc) {
        const __hip_bfloat16* w2c = w2r + oc * 128;
        #pragma unroll
        for (int nf = 0; nf < 2; ++nf)
            #pragma unroll
            for (int ks = 0; ks < 4; ++ks)
                f2[nf * 4 + ks] = *(const short8*)(w2c + (size_t)(nf * 16) * FH + ks * 32);
    };
    auto gelu_store = [&](int oc) {
        float b1v = b1s[oc];
        #pragma unroll
        for (int mi = 0; mi < 9; ++mi) {
            #pragma unroll
            for (int r = 0; r < 4; ++r) {
                float v = pre[mi][r] + b1v;
                float y = 1.5957691216057308f * v * fmaf(v * v, 0.044715f, 1.0f);
                float gl = __fdividef(v, 1.0f + __expf(-y));
                int row = mi * 16 + kg * 4 + r;
                int pp = (row ^ (row >> 2)) & 7;
                hs[row * 128 + ((cgw ^ pp) << 3) + lr7] = __float2bfloat16(gl);
            }
        }
    };

    #pragma unroll 1
    for (int tile = t0; tile < ntiles; tile += 16) {
        const int base = tile * MT;
        const int nv = min(MT, n - base);

        // gather MT x-rows into swizzled xs: 4 threads/row, 10x16B each
        {
            int row = tid >> 2, part = tid & 3;
            {
                int pr = list[e * BB + base + min(row, nv - 1)];
                const ulonglong2* src = (const ulonglong2*)(xbf + (size_t)(pr >> 1) * XD) + part * 10;
                int r7 = row & 7;
                #pragma unroll
                for (int i = 0; i < 10; ++i) {
                    int u = part * 10 + i;
                    *(ulonglong2*)&xs[row * 320 + ((u ^ r7) << 3)] = src[i];
                }
            }
            if (tid < 64) {
                int row2 = 128 + (tid >> 2);
                int pr = list[e * BB + base + min(row2, nv - 1)];
                const ulonglong2* src = (const ulonglong2*)(xbf + (size_t)(pr >> 1) * XD) + part * 10;
                int r7 = row2 & 7;
                #pragma unroll
                for (int i = 0; i < 10; ++i) {
                    int u = part * 10 + i;
                    *(ulonglong2*)&xs[row2 * 320 + ((u ^ r7) << 3)] = src[i];
                }
            }
        }
        wg_barrier();  // xs ready (prev tile's hs reads all completed pre-barrier)

        #pragma unroll
        for (int mi = 0; mi < 9; ++mi) {
            acc[mi][0] = (f32x4){0.f, 0.f, 0.f, 0.f};
            acc[mi][1] = (f32x4){0.f, 0.f, 0.f, 0.f};
        }

        // ---- prologue: GEMM1(0) + GELU(0) (no barrier needed before store) ----
        {
            const __hip_bfloat16* w1c = w1r;
            short8 f1[10];
            #pragma unroll
            for (int ks = 0; ks < 10; ++ks) f1[ks] = *(const short8*)(w1c + ks * 32);
            #pragma unroll
            for (int mi = 0; mi < 9; ++mi) pre[mi] = (f32x4){0.f, 0.f, 0.f, 0.f};
            #pragma unroll
            for (int ks = 0; ks < 10; ++ks) g1step(f1[ks], ks);
            loadf2(0);
            gelu_store(0);
        }
        wg_barrier();  // hs(0) visible

        // ---- pipelined chunks 1..7: merged GEMM2(oc-1) + GEMM1(oc) ----
        #pragma unroll 1
        for (int oc = 1; oc < 8; ++oc) {
            const __hip_bfloat16* w1c = w1r + (size_t)(oc * 128) * XD;
            short8 f1[10];
            #pragma unroll
            for (int ks = 0; ks < 10; ++ks) f1[ks] = *(const short8*)(w1c + ks * 32);
            #pragma unroll
            for (int mi = 0; mi < 9; ++mi) pre[mi] = (f32x4){0.f, 0.f, 0.f, 0.f};
            // coarse manual interleave of the two GEMMs in one region
            g1step(f1[0], 0); g1step(f1[1], 1);
            g2step(0);
            g1step(f1[2], 2); g1step(f1[3], 3); g1step(f1[4], 4);
            g2step(1);
            g1step(f1[5], 5); g1step(f1[6], 6); g1step(f1[7], 7);
            g2step(2);
            g1step(f1[8], 8); g1step(f1[9], 9);
            g2step(3);
            loadf2(oc);    // flies across GELU + barriers into next region
            wg_barrier();  // A: all waves done reading hs(oc-1)
            gelu_store(oc);
            wg_barrier();  // B: hs(oc) visible
        }

        // ---- epilogue chunk: GEMM2(7) ----
        #pragma unroll
        for (int ks = 0; ks < 4; ++ks) g2step(ks);

        // epilogue: +b2, *routing weight, scatter bf16 rows to per-pair scratch
        #pragma unroll
        for (int r = 0; r < 4; ++r) {
            #pragma unroll
            for (int mi = 0; mi < 9; ++mi) {
                int rr = mi * 16 + kg * 4 + r;
                if (rr < nv) {
                    int pair = list[e * BB + base + rr];
                    float w = topw[pair];
                    __hip_bfloat16* dst = tmp + (size_t)pair * HH + wv * 32;
                    dst[l15]      = __float2bfloat16(w * (acc[mi][0][r] + b2v[0]));
                    dst[16 + l15] = __float2bfloat16(w * (acc[mi][1][r] + b2v[1]));
                }
            }
        }
        // next tile's gather: last hs reads (GEMM2(7)) complete before the
        // gather barrier; gather writes xs only.
    }
}

// ---------------- combine the two expert slots (bf16 tmp -> f32 out) ----------------
__global__ void combine_kernel(const __hip_bfloat16* __restrict__ tmp, float* __restrict__ out) {
    int i = blockIdx.x * blockDim.x + threadIdx.x;  // float4 index over [B*256/4)
    int b = i >> 6;
    int d4 = i & 63;
    const ushort4* t0 = (const ushort4*)(tmp + (size_t)b * 512);
    ushort4 a = t0[d4];
    ushort4 c = t0[64 + d4];
    union { unsigned short u; __hip_bfloat16 b; } cv;
    float4 o;
    { cv.u = a.x; float fa = __bfloat162float(cv.b); cv.u = c.x; o.x = fa + __bfloat162float(cv.b); }
    { cv.u = a.y; float fa = __bfloat162float(cv.b); cv.u = c.y; o.y = fa + __bfloat162float(cv.b); }
    { cv.u = a.z; float fa = __bfloat162float(cv.b); cv.u = c.z; o.z = fa + __bfloat162float(cv.b); }
    { cv.u = a.w; float fa = __bfloat162float(cv.b); cv.u = c.w; o.w = fa + __bfloat162float(cv.b); }
    ((float4*)out)[i] = o;
}

extern "C" void kernel_launch(void* const* d_in, const int* in_sizes, int n_in,
                              void* d_out, int out_size, void* d_ws, size_t ws_size,
                              hipStream_t stream) {
    const float* h   = (const float*)d_in[0];
    const float* ce  = (const float*)d_in[1];
    const float* anc = (const float*)d_in[2];
    const float* W1  = (const float*)d_in[3];
    const float* b1  = (const float*)d_in[4];
    const float* W2  = (const float*)d_in[5];
    const float* b2  = (const float*)d_in[6];
    const float* gum = (const float*)d_in[7];
    float* out = (float*)d_out;

    char* ws = (char*)d_ws;
    size_t off = 0;
    auto alloc = [&](size_t bytes) {
        char* p = ws + off;
        off = (off + bytes + 255) & ~(size_t)255;
        return p;
    };
    __hip_bfloat16* W1bf = (__hip_bfloat16*)alloc((size_t)EE * FH * XD * 2);
    __hip_bfloat16* W2bf = (__hip_bfloat16*)alloc((size_t)EE * HH * FH * 2);
    __hip_bfloat16* xbf  = (__hip_bfloat16*)alloc((size_t)BB * XD * 2);
    __hip_bfloat16* tmp  = (__hip_bfloat16*)alloc((size_t)BB * 2 * HH * 2);
    float* topw = (float*)alloc((size_t)BB * 2 * 4);
    int*   tope = (int*)alloc((size_t)BB * 2 * 4);
    int*   list = (int*)alloc((size_t)EE * BB * 4);
    int*   cnt  = (int*)alloc(EE * CNTP * 4);
    float* anorm = (float*)alloc(EE * CC * 4);
    float* partial = (float*)alloc(64 * EE * 4);

    hipMemsetAsync(cnt, 0, EE * CNTP * 4, stream);
    anorm_kernel<<<1, 256, 0, stream>>>(anc, anorm);
    router_kernel<<<BB / 16, 256, 0, stream>>>(ce, gum, anorm, topw, tope);
    assign_kernel<<<2 * BB / 512, 256, 0, stream>>>(tope, list, cnt);
    convert_w_kernel<<<((EE * FH * XD + EE * HH * FH) / 4 + 255) / 256, 256, 0, stream>>>(W1, W2, W1bf, W2bf);
    convert_x_kernel<<<(BB * XD / 4 + 255) / 256, 256, 0, stream>>>(h, ce, xbf);
    aux_partial_kernel<<<64, 256, 0, stream>>>(topw, tope, partial);
    aux_final_kernel<<<1, 64, 0, stream>>>(partial, out);
    moe_kernel<<<dim3(256), 512, 0, stream>>>(xbf, W1bf, W2bf, b1, b2, list, cnt, topw, tmp);
    combine_kernel<<<(BB * HH / 4) / 256, 256, 0, stream>>>(tmp, out);
}

// Round 11
// 133.483 us; speedup vs baseline: 1.2069x; 1.2069x over previous
//
#include <hip/hip_runtime.h>
#include <hip/hip_bf16.h>

#define BB 16384
#define EE 16
#define HH 256
#define CC 64
#define XD 320   // H + C
#define FH 1024  // 4H
#define CNTP 16  // cnt padding stride (one counter per 64B line)
#define MT 144   // token buffer per block (9 x 16)

typedef __attribute__((ext_vector_type(8))) short short8;
typedef __attribute__((ext_vector_type(4))) float f32x4;

__device__ inline unsigned short bfu(float x) {
    union { __hip_bfloat16 b; unsigned short u; } c;
    c.b = __float2bfloat16(x);
    return c.u;
}

// raw workgroup barrier: drains LDS ops only, leaves global loads in flight
__device__ inline void wg_barrier() {
    asm volatile("s_waitcnt lgkmcnt(0)" ::: "memory");
    __builtin_amdgcn_s_barrier();
    asm volatile("" ::: "memory");
}

// ---------------- fused convert: W1,W2,x -> bf16 ----------------
__global__ void convert_kernel(const float* __restrict__ W1, const float* __restrict__ W2,
                               const float* __restrict__ h, const float* __restrict__ ce,
                               __hip_bfloat16* __restrict__ W1bf, __hip_bfloat16* __restrict__ W2bf,
                               __hip_bfloat16* __restrict__ xbf) {
    int i = blockIdx.x * blockDim.x + threadIdx.x;
    const int n1 = EE * FH * XD / 4;
    const int n2 = EE * HH * FH / 4;
    const int nx = BB * XD / 4;
    if (i < n1) {
        float4 v = ((const float4*)W1)[i];
        ushort4 o; o.x = bfu(v.x); o.y = bfu(v.y); o.z = bfu(v.z); o.w = bfu(v.w);
        ((ushort4*)W1bf)[i] = o;
    } else if (i < n1 + n2) {
        int j = i - n1;
        float4 v = ((const float4*)W2)[j];
        ushort4 o; o.x = bfu(v.x); o.y = bfu(v.y); o.z = bfu(v.z); o.w = bfu(v.w);
        ((ushort4*)W2bf)[j] = o;
    } else if (i < n1 + n2 + nx) {
        int j = i - n1 - n2;
        int i4 = j * 4;
        int b = i4 / XD;
        int c = i4 % XD;
        float4 v;
        if (c < HH) v = *(const float4*)&h[b * HH + c];
        else        v = *(const float4*)&ce[b * CC + (c - HH)];
        ushort4 o; o.x = bfu(v.x); o.y = bfu(v.y); o.z = bfu(v.z); o.w = bfu(v.w);
        ((ushort4*)xbf)[j] = o;
    }
}

// ---------------- router (anchor-norm fused): 16 tok x 16 experts per block ----------------
__global__ __launch_bounds__(256) void router_kernel(
    const float* __restrict__ code_emb, const float* __restrict__ gumbel,
    const float* __restrict__ anchor,
    float* __restrict__ topw, int* __restrict__ tope)
{
    __shared__ float an_s[EE][68];
    __shared__ float ce_s[16][68];
    __shared__ float inrm[16];
    __shared__ float ainv[16];
    const int tid = threadIdx.x;

    {
        int idx = tid * 4;
        int r = idx >> 6, k = idx & 63;
        *(float4*)&an_s[r][k] = *(const float4*)&anchor[idx];
        *(float4*)&ce_s[r][k] = *(const float4*)&code_emb[blockIdx.x * 1024 + idx];
    }
    __syncthreads();

    if (tid < EE) {
        float s = 0.f;
        #pragma unroll
        for (int k = 0; k < 64; ++k) { float a = an_s[tid][k]; s += a * a; }
        ainv[tid] = 1.0f / fmaxf(sqrtf(s), 1e-8f);
    } else if (tid < 2 * EE) {
        int t = tid - EE;
        float s = 0.f;
        #pragma unroll
        for (int k = 0; k < 64; ++k) { float c = ce_s[t][k]; s += c * c; }
        inrm[t] = 0.125f / fmaxf(sqrtf(s), 1e-8f);
    }
    __syncthreads();

    const int tok = tid >> 4;
    const int e = tid & 15;
    float dot = 0.f;
    #pragma unroll
    for (int k = 0; k < 64; ++k) dot += ce_s[tok][k] * an_s[e][k];

    const int b = blockIdx.x * 16 + tok;
    float z = (dot * inrm[tok] * ainv[e] + gumbel[b * EE + e]) * 2.0f;  // /TAU

    float m = z;
    #pragma unroll
    for (int off = 1; off < 16; off <<= 1) m = fmaxf(m, __shfl_xor(m, off, 64));
    float p = expf(z - m);
    float s = p;
    #pragma unroll
    for (int off = 1; off < 16; off <<= 1) s += __shfl_xor(s, off, 64);
    float w = p / s;

    const int lbase = (tid & 63) & 48;
    float best = -1.f, second = -1.f;
    int bi = 0, si = 0;
    #pragma unroll
    for (int j = 0; j < EE; ++j) {
        float wj = __shfl(w, lbase + j, 64);
        if (wj > best) { second = best; si = bi; best = wj; bi = j; }
        else if (wj > second) { second = wj; si = j; }
    }
    if (e == 0) {
        topw[b * 2] = best;       tope[b * 2] = bi;
        topw[b * 2 + 1] = second; tope[b * 2 + 1] = si;
    }
}

// ---------------- counting-sort assignment + aux partial (fused) ----------------
__global__ __launch_bounds__(256) void assign_kernel(
    const int* __restrict__ tope, const float* __restrict__ topw,
    int* __restrict__ list, int* __restrict__ cnt, float* __restrict__ partial)
{
    __shared__ int lcnt[EE];
    __shared__ int bas[EE];
    __shared__ float ls[256][EE + 1];
    const int tid = threadIdx.x;
    #pragma unroll
    for (int e = 0; e < EE; ++e) ls[tid][e] = 0.f;
    if (tid < EE) lcnt[tid] = 0;
    __syncthreads();
    const int p0 = blockIdx.x * 512;
    const int e0 = tope[p0 + tid];
    const int e1 = tope[p0 + 256 + tid];
    ls[tid][e0] += topw[p0 + tid];
    ls[tid][e1] += topw[p0 + 256 + tid];
    const int r0 = atomicAdd(&lcnt[e0], 1);
    const int r1 = atomicAdd(&lcnt[e1], 1);
    __syncthreads();
    if (tid < EE) {
        bas[tid] = atomicAdd(&cnt[tid * CNTP], lcnt[tid]);
        float s = 0.f;
        for (int r = 0; r < 256; ++r) s += ls[r][tid];
        partial[blockIdx.x * EE + tid] = s;
    }
    __syncthreads();
    list[e0 * BB + bas[e0] + r0] = p0 + tid;
    list[e1 * BB + bas[e1] + r1] = p0 + 256 + tid;
}

__global__ void aux_final_kernel(const float* __restrict__ partial, float* __restrict__ out) {
    __shared__ float counts[EE];
    int tid = threadIdx.x;
    if (tid < EE) {
        float s = 0.f;
        for (int bk = 0; bk < 64; ++bk) s += partial[bk * EE + tid];
        counts[tid] = s;
    }
    __syncthreads();
    if (tid == 0) {
        float total = 0.f;
        for (int e = 0; e < EE; ++e) total += counts[e];
        float mean = total / EE;
        float var = 0.f;
        for (int e = 0; e < EE; ++e) { float d = counts[e] - mean; var += d * d; }
        var /= (EE - 1);
        float ent = 0.f;
        for (int e = 0; e < EE; ++e) { float ld = counts[e] / total; ent -= ld * logf(ld + 1e-12f); }
        out[(size_t)BB * HH] = 0.5f * (sqrtf(var) + ent);
    }
}

// ---------------- fused sparse MoE MLP ----------------
// Grid 256 = 16 experts x 16 blocks; even token split m = ceil(n/16) <= 144.
// GEMM1: waves = 2 M-groups (rows 0-79: 5 mi / 80-143: 4 mi) x 4 col-groups of
// 32 cols -> each xs A-read feeds TWO MFMAs (reads/chunk/CU 720 -> 360; W1
// L2 traffic 2x, cheap at ~56 B/cyc/CU). GEMM2: 8 waves x 32 d-cols (as R9).
// 2 raw barriers per chunk; f2 issued before barrier A (flies across).
__global__ __launch_bounds__(512, 2) void moe_kernel(
    const __hip_bfloat16* __restrict__ xbf,
    const __hip_bfloat16* __restrict__ W1bf,
    const __hip_bfloat16* __restrict__ W2bf,
    const float* __restrict__ b1, const float* __restrict__ b2,
    const int* __restrict__ list, const int* __restrict__ cnt,
    const float* __restrict__ topw,
    __hip_bfloat16* __restrict__ tmp)
{
    __shared__ __hip_bfloat16 xs[MT * 320];   // 90 KB, XOR-swizzled 16B granules
    __shared__ __hip_bfloat16 hs[MT * 128];   // 36 KB, single buffer, swizzled
    const int e = blockIdx.x & 15;   // XCD = bid%8 = e%8
    const int t0 = blockIdx.x >> 4;  // 0..15
    const int n = cnt[e * CNTP];
    if (n <= 0) return;
    const int m = min((n + 15) >> 4, MT);  // even split; >MT impossible (+5.8 sigma)
    const int tid = threadIdx.x;
    const int lane = tid & 63;
    const int wv = tid >> 6;     // 0..7
    const int mg = wv >> 2;      // 0..1: GEMM1 M-group
    const int cg = wv & 3;       // 0..3: GEMM1 col-group (32 cols)
    const int nmi = mg ? 4 : 5;  // mi count (rows 80-143 vs 0-79)
    const int rbase = mg * 80;
    const int l15 = lane & 15;
    const int kg = lane >> 4;    // 0..3
    const int lr7 = l15 & 7;

    const __hip_bfloat16* w1a = W1bf + (size_t)e * FH * XD + (size_t)(cg * 32 + l15) * XD + kg * 8;
    const __hip_bfloat16* w1b = w1a + (size_t)16 * XD;
    const __hip_bfloat16* w2r = W2bf + (size_t)e * HH * FH + (size_t)(wv * 32 + l15) * FH + kg * 8;
    const float* b1r = b1 + e * FH + cg * 32 + l15;
    float b2v[2];
    b2v[0] = b2[e * HH + wv * 32 + l15];
    b2v[1] = b2[e * HH + wv * 32 + 16 + l15];

    f32x4 acc[9][2];
    short8 f2[8];

    #pragma unroll 1
    for (int base = t0 * m; base < n; base += 16 * m) {
        const int nv = min(m, n - base);

        // gather up to 144 x-rows into swizzled xs: 4 threads/row, 10x16B each
        {
            int row = tid >> 2, part = tid & 3;
            {
                int pr = list[e * BB + base + min(row, nv - 1)];
                const ulonglong2* src = (const ulonglong2*)(xbf + (size_t)(pr >> 1) * XD) + part * 10;
                int r7 = row & 7;
                #pragma unroll
                for (int i = 0; i < 10; ++i) {
                    int u = part * 10 + i;
                    *(ulonglong2*)&xs[row * 320 + ((u ^ r7) << 3)] = src[i];
                }
            }
            if (tid < 64) {
                int row2 = 128 + (tid >> 2);
                int pr = list[e * BB + base + min(row2, nv - 1)];
                const ulonglong2* src = (const ulonglong2*)(xbf + (size_t)(pr >> 1) * XD) + part * 10;
                int r7 = row2 & 7;
                #pragma unroll
                for (int i = 0; i < 10; ++i) {
                    int u = part * 10 + i;
                    *(ulonglong2*)&xs[row2 * 320 + ((u ^ r7) << 3)] = src[i];
                }
            }
        }
        wg_barrier();  // xs ready

        #pragma unroll
        for (int mi = 0; mi < 9; ++mi) {
            acc[mi][0] = (f32x4){0.f, 0.f, 0.f, 0.f};
            acc[mi][1] = (f32x4){0.f, 0.f, 0.f, 0.f};
        }

        #pragma unroll 1
        for (int oc = 0; oc < 8; ++oc) {
            // GEMM1: this wave's 32 cols x its M-group rows, K=320
            const __hip_bfloat16* wca = w1a + (size_t)(oc * 128) * XD;
            const __hip_bfloat16* wcb = w1b + (size_t)(oc * 128) * XD;
            float b1v0 = b1r[oc * 128];
            float b1v1 = b1r[oc * 128 + 16];
            f32x4 pre[5][2];
            #pragma unroll
            for (int mi = 0; mi < 5; ++mi) {
                pre[mi][0] = (f32x4){0.f, 0.f, 0.f, 0.f};
                pre[mi][1] = (f32x4){0.f, 0.f, 0.f, 0.f};
            }
            #pragma unroll
            for (int ks = 0; ks < 10; ++ks) {
                short8 fa = *(const short8*)(wca + ks * 32);
                short8 fb = *(const short8*)(wcb + ks * 32);
                #pragma unroll
                for (int mi = 0; mi < 5; ++mi) {
                    if (mi < nmi) {  // wave-uniform
                        short8 a = *(const short8*)&xs[(rbase + mi * 16 + l15) * 320 + (((ks * 4 + kg) ^ lr7) << 3)];
                        pre[mi][0] = __builtin_amdgcn_mfma_f32_16x16x32_bf16(a, fa, pre[mi][0], 0, 0, 0);
                        pre[mi][1] = __builtin_amdgcn_mfma_f32_16x16x32_bf16(a, fb, pre[mi][1], 0, 0, 0);
                    }
                }
            }
            // issue W2(oc) early: in flight across GELU + barriers
            {
                const __hip_bfloat16* w2c = w2r + oc * 128;
                #pragma unroll
                for (int nf = 0; nf < 2; ++nf)
                    #pragma unroll
                    for (int ks = 0; ks < 4; ++ks)
                        f2[nf * 4 + ks] = *(const short8*)(w2c + (size_t)(nf * 16) * FH + ks * 32);
            }
            wg_barrier();  // A: all waves done reading hs(oc-1)
            // bias + tanh-GELU -> hs (swizzled; wave writes its M-rows x 32 cols)
            #pragma unroll
            for (int mi = 0; mi < 5; ++mi) {
                if (mi < nmi) {
                    #pragma unroll
                    for (int nf = 0; nf < 2; ++nf) {
                        float b1v = nf ? b1v1 : b1v0;
                        #pragma unroll
                        for (int r = 0; r < 4; ++r) {
                            float v = pre[mi][nf][r] + b1v;
                            float y = 1.5957691216057308f * v * fmaf(v * v, 0.044715f, 1.0f);
                            float gl = __fdividef(v, 1.0f + __expf(-y));
                            int row = rbase + mi * 16 + kg * 4 + r;
                            int u = cg * 4 + nf * 2 + (l15 >> 3);
                            hs[row * 128 + ((u ^ (row & 7)) << 3) + lr7] = __float2bfloat16(gl);
                        }
                    }
                }
            }
            wg_barrier();  // B: hs(oc) visible
            // GEMM2: acc[144 tok][32 d-cols per wave] += hid @ W2^T, K=128 slice
            #pragma unroll
            for (int ks = 0; ks < 4; ++ks) {
                #pragma unroll
                for (int mi = 0; mi < 9; ++mi) {
                    int row = mi * 16 + l15;
                    short8 a2 = *(const short8*)&hs[row * 128 + (((ks * 4 + kg) ^ (row & 7)) << 3)];
                    acc[mi][0] = __builtin_amdgcn_mfma_f32_16x16x32_bf16(a2, f2[ks], acc[mi][0], 0, 0, 0);
                    acc[mi][1] = __builtin_amdgcn_mfma_f32_16x16x32_bf16(a2, f2[4 + ks], acc[mi][1], 0, 0, 0);
                }
            }
        }

        // epilogue: +b2, *routing weight, scatter bf16 rows to per-pair scratch
        #pragma unroll
        for (int r = 0; r < 4; ++r) {
            #pragma unroll
            for (int mi = 0; mi < 9; ++mi) {
                int rr = mi * 16 + kg * 4 + r;
                if (rr < nv) {
                    int pair = list[e * BB + base + rr];
                    float w = topw[pair];
                    __hip_bfloat16* dst = tmp + (size_t)pair * HH + wv * 32;
                    dst[l15]      = __float2bfloat16(w * (acc[mi][0][r] + b2v[0]));
                    dst[16 + l15] = __float2bfloat16(w * (acc[mi][1][r] + b2v[1]));
                }
            }
        }
        // next gather ordered by barrier B of the last chunk
    }
}

// ---------------- combine the two expert slots (bf16 tmp -> f32 out) ----------------
__global__ void combine_kernel(const __hip_bfloat16* __restrict__ tmp, float* __restrict__ out) {
    int i = blockIdx.x * blockDim.x + threadIdx.x;  // float4 index over [B*256/4)
    int b = i >> 6;
    int d4 = i & 63;
    const ushort4* t0 = (const ushort4*)(tmp + (size_t)b * 512);
    ushort4 a = t0[d4];
    ushort4 c = t0[64 + d4];
    union { unsigned short u; __hip_bfloat16 b; } cv;
    float4 o;
    { cv.u = a.x; float fa = __bfloat162float(cv.b); cv.u = c.x; o.x = fa + __bfloat162float(cv.b); }
    { cv.u = a.y; float fa = __bfloat162float(cv.b); cv.u = c.y; o.y = fa + __bfloat162float(cv.b); }
    { cv.u = a.z; float fa = __bfloat162float(cv.b); cv.u = c.z; o.z = fa + __bfloat162float(cv.b); }
    { cv.u = a.w; float fa = __bfloat162float(cv.b); cv.u = c.w; o.w = fa + __bfloat162float(cv.b); }
    ((float4*)out)[i] = o;
}

extern "C" void kernel_launch(void* const* d_in, const int* in_sizes, int n_in,
                              void* d_out, int out_size, void* d_ws, size_t ws_size,
                              hipStream_t stream) {
    const float* h   = (const float*)d_in[0];
    const float* ce  = (const float*)d_in[1];
    const float* anc = (const float*)d_in[2];
    const float* W1  = (const float*)d_in[3];
    const float* b1  = (const float*)d_in[4];
    const float* W2  = (const float*)d_in[5];
    const float* b2  = (const float*)d_in[6];
    const float* gum = (const float*)d_in[7];
    float* out = (float*)d_out;

    char* ws = (char*)d_ws;
    size_t off = 0;
    auto alloc = [&](size_t bytes) {
        char* p = ws + off;
        off = (off + bytes + 255) & ~(size_t)255;
        return p;
    };
    __hip_bfloat16* W1bf = (__hip_bfloat16*)alloc((size_t)EE * FH * XD * 2);
    __hip_bfloat16* W2bf = (__hip_bfloat16*)alloc((size_t)EE * HH * FH * 2);
    __hip_bfloat16* xbf  = (__hip_bfloat16*)alloc((size_t)BB * XD * 2);
    __hip_bfloat16* tmp  = (__hip_bfloat16*)alloc((size_t)BB * 2 * HH * 2);
    float* topw = (float*)alloc((size_t)BB * 2 * 4);
    int*   tope = (int*)alloc((size_t)BB * 2 * 4);
    int*   list = (int*)alloc((size_t)EE * BB * 4);
    int*   cnt  = (int*)alloc(EE * CNTP * 4);
    float* partial = (float*)alloc(64 * EE * 4);

    const int n1 = EE * FH * XD / 4;
    const int n2 = EE * HH * FH / 4;
    const int nx = BB * XD / 4;

    hipMemsetAsync(cnt, 0, EE * CNTP * 4, stream);
    convert_kernel<<<(n1 + n2 + nx + 255) / 256, 256, 0, stream>>>(W1, W2, h, ce, W1bf, W2bf, xbf);
    router_kernel<<<BB / 16, 256, 0, stream>>>(ce, gum, anc, topw, tope);
    assign_kernel<<<2 * BB / 512, 256, 0, stream>>>(tope, topw, list, cnt, partial);
    aux_final_kernel<<<1, 64, 0, stream>>>(partial, out);
    moe_kernel<<<dim3(256), 512, 0, stream>>>(xbf, W1bf, W2bf, b1, b2, list, cnt, topw, tmp);
    combine_kernel<<<(BB * HH / 4) / 256, 256, 0, stream>>>(tmp, out);
}